// Round 16
// baseline (266.889 us; speedup 1.0000x reference)
//
#include <hip/hip_runtime.h>
#include <hip/hip_bf16.h>

#define NODES  100000
#define EDGES  1600000
#define GRAPHS 4096
#define HID    128
#define INDIM  14
#define NPART  8
#define PART_SZ ((NODES + NPART - 1) / NPART)  // 12500
#define BPG    256        // blocks per partition group (fill)
#define CSTRIDE 64        // fixed CSR bucket stride; P(deg>=64 | Poisson(16)) ~ 2e-18
#define LDST   136        // LDS tile row stride in bf16 (272B: 16B-aligned)
#define LDSTF  132        // fp32 LDS tile row stride

typedef float f32x4 __attribute__((ext_vector_type(4)));
typedef short bf16x8 __attribute__((ext_vector_type(8)));
typedef int   i32x4 __attribute__((ext_vector_type(4)));

__device__ __forceinline__ unsigned packbf(float a, float b) {
    __hip_bfloat162 t;
    t.x = __float2bfloat16(a);
    t.y = __float2bfloat16(b);
    return *(unsigned*)&t;
}
__device__ __forceinline__ void acc8(float* a, uint4 v) {
    a[0] += __uint_as_float(v.x << 16);
    a[1] += __uint_as_float(v.x & 0xffff0000u);
    a[2] += __uint_as_float(v.y << 16);
    a[3] += __uint_as_float(v.y & 0xffff0000u);
    a[4] += __uint_as_float(v.z << 16);
    a[5] += __uint_as_float(v.z & 0xffff0000u);
    a[6] += __uint_as_float(v.w << 16);
    a[7] += __uint_as_float(v.w & 0xffff0000u);
}

// ---------------- prep: zero cnt/pooled + pad x to fp32 [NODES][16] ----------------

__global__ void k_prep2(int* __restrict__ cnt, float* __restrict__ pooled,
                        const float* __restrict__ x, float* __restrict__ xf) {
    int i = blockIdx.x * 256 + threadIdx.x;
    if (i < NODES) cnt[i] = 0;
    if (i < GRAPHS * HID) pooled[i] = 0.f;
    if (i < NODES * 16) {
        int node = i >> 4, c = i & 15;
        xf[i] = c < INDIM ? x[node * INDIM + c] : 0.f;
    }
}

// ---------------- bucket-CSR build (single-pass, XCD-range-partitioned) ----------------

__global__ __launch_bounds__(256) void k_fill_fx(const i32x4* __restrict__ src4,
                                                 const i32x4* __restrict__ dst4,
                                                 int* __restrict__ cnt,
                                                 int* __restrict__ csr) {
    const int g = blockIdx.x & (NPART - 1);
    const int blk = blockIdx.x >> 3;
    const int lo = g * PART_SZ;
    const int n4 = EDGES / 4;
    for (int e4 = blk * 256 + threadIdx.x; e4 < n4; e4 += BPG * 256) {
        i32x4 d = __builtin_nontemporal_load(&dst4[e4]);
        i32x4 s = __builtin_nontemporal_load(&src4[e4]);
#pragma unroll
        for (int j = 0; j < 4; j++) {
            int dj = d[j];
            if ((unsigned)(dj - lo) < PART_SZ) {
                int pos = atomicAdd(&cnt[dj], 1);
                if (pos < CSTRIDE) csr[dj * CSTRIDE + pos] = s[j];
            }
        }
    }
}

// ---------------- weight convert: 4x W[k][n] fp32 -> Wt[n][k] bf16 ----------------

__global__ void k_w_cvt4(const float* __restrict__ Wa, const float* __restrict__ Wb,
                         const float* __restrict__ Wc, const float* __restrict__ Wd,
                         __hip_bfloat16* __restrict__ Ta, __hip_bfloat16* __restrict__ Tb,
                         __hip_bfloat16* __restrict__ Tc, __hip_bfloat16* __restrict__ Td) {
    int which = blockIdx.x >> 6;
    int idx = (blockIdx.x & 63) * 256 + threadIdx.x;  // 16384 per matrix
    const float* W = which == 0 ? Wa : which == 1 ? Wb : which == 2 ? Wc : Wd;
    __hip_bfloat16* T = which == 0 ? Ta : which == 1 ? Tb : which == 2 ? Tc : Td;
    int n = idx & 127, k = idx >> 7;
    T[n * HID + k] = __float2bfloat16(W[k * HID + n]);
}

// ---------------- MFMA slice helper (16-row tile, wave does 32-col slice) ----------------
// A frag: lane rl=l&15 -> row rl, kb=l>>4 -> k = kc*32+kb*8..+7.
// C/D: col = n*16+rl, row = kb*4+j  [verified mapping].

template <int RELU, int TO_LDS>
__device__ __forceinline__ void mfma_slice16(const __hip_bfloat16* lds_in,
                                             const __hip_bfloat16* __restrict__ Wt,
                                             const float* __restrict__ bias,
                                             __hip_bfloat16* lds_out,
                                             __hip_bfloat16* __restrict__ gout,
                                             int row0, int tid) {
    const int wave = tid >> 6;
    const int lane = tid & 63;
    const int rl = lane & 15;
    const int kb = lane >> 4;

    bf16x8 afrag[4];
#pragma unroll
    for (int kc = 0; kc < 4; kc++)
        afrag[kc] = *(const bf16x8*)(lds_in + rl * LDST + kc * 32 + kb * 8);

#pragma unroll
    for (int s = 0; s < 2; s++) {
        const int n = wave * 2 + s;
        f32x4 acc = (f32x4){0.f, 0.f, 0.f, 0.f};
        const __hip_bfloat16* Bp = Wt + (size_t)(n * 16 + rl) * HID + kb * 8;
#pragma unroll
        for (int kc = 0; kc < 4; kc++) {
            bf16x8 bfrag = *(const bf16x8*)(Bp + kc * 32);
            acc = __builtin_amdgcn_mfma_f32_16x16x32_bf16(afrag[kc], bfrag, acc, 0, 0, 0);
        }
        const int col = n * 16 + rl;
        const float bv = bias[col];
#pragma unroll
        for (int j = 0; j < 4; j++) {
            int rloc = kb * 4 + j;
            float v = acc[j] + bv;
            if (RELU) v = fmaxf(v, 0.f);
            if (TO_LDS)
                lds_out[rloc * LDST + col] = __float2bfloat16(v);
            else
                gout[(size_t)(row0 + rloc) * HID + col] = __float2bfloat16(v);
        }
    }
}

// ---------------- layer 1 fused: 64 nodes/block, float4 gather (4 lanes/node) ----------------

__global__ __launch_bounds__(256) void k_l1(const float4* __restrict__ xf,
                                            const int* __restrict__ cnt,
                                            const int* __restrict__ csr,
                                            const float* __restrict__ W1a,
                                            const float* __restrict__ b1a,
                                            const __hip_bfloat16* __restrict__ Wt1b,
                                            const float* __restrict__ b1b,
                                            __hip_bfloat16* __restrict__ h1) {
    __shared__ float p14[64][16];
    __shared__ __hip_bfloat16 t[64 * LDST];
    const int row0 = blockIdx.x * 64;
    const int tid = threadIdx.x;

    // phase 1: 64 nodes x 4 lanes, float4 gather of padded x rows (64B each)
    {
        int nl = tid >> 2, q = tid & 3;
        int node = row0 + nl;
        float4 acc = make_float4(0.f, 0.f, 0.f, 0.f);
        if (node < NODES) {
            int len = cnt[node];
            if (len > CSTRIDE) len = CSTRIDE;
            const int* cp = csr + (size_t)node * CSTRIDE;
            acc = xf[(size_t)node * 4 + q];
            int e = 0;
            for (; e + 3 < len; e += 4) {
                int s0 = cp[e], s1 = cp[e + 1], s2 = cp[e + 2], s3 = cp[e + 3];
                float4 v0 = xf[(size_t)s0 * 4 + q];
                float4 v1 = xf[(size_t)s1 * 4 + q];
                float4 v2 = xf[(size_t)s2 * 4 + q];
                float4 v3 = xf[(size_t)s3 * 4 + q];
                acc.x += (v0.x + v1.x) + (v2.x + v3.x);
                acc.y += (v0.y + v1.y) + (v2.y + v3.y);
                acc.z += (v0.z + v1.z) + (v2.z + v3.z);
                acc.w += (v0.w + v1.w) + (v2.w + v3.w);
            }
            for (; e < len; e++) {
                float4 v = xf[(size_t)cp[e] * 4 + q];
                acc.x += v.x; acc.y += v.y; acc.z += v.z; acc.w += v.w;
            }
        }
        *(float4*)&p14[nl][q * 4] = acc;
    }
    __syncthreads();

    // phase 2: K=14 VALU GEMM + relu -> bf16 LDS tile (64 rows x 32 quads, 8/thread)
    for (int i = tid; i < 2048; i += 256) {
        int r = i >> 5, c4 = (i & 31) << 2;
        float4 bv = *(const float4*)&b1a[c4];
        float ax = bv.x, ay = bv.y, az = bv.z, aw = bv.w;
#pragma unroll
        for (int k = 0; k < INDIM; k++) {
            float a = p14[r][k];
            float4 w = *(const float4*)&W1a[k * HID + c4];
            ax += a * w.x; ay += a * w.y; az += a * w.z; aw += a * w.w;
        }
        unsigned p0 = packbf(fmaxf(ax, 0.f), fmaxf(ay, 0.f));
        unsigned p1 = packbf(fmaxf(az, 0.f), fmaxf(aw, 0.f));
        *(uint2*)&t[r * LDST + c4] = make_uint2(p0, p1);
    }
    __syncthreads();

    // phase 3: 4 waves x 16 rows, each wave full 128 cols (8 n-frags) -> h1
    {
        const int wave = tid >> 6;
        const int lane = tid & 63;
        const int rl = lane & 15;
        const int kb = lane >> 4;
        const __hip_bfloat16* Ap = t + (wave * 16 + rl) * LDST + kb * 8;
        bf16x8 afrag[4];
#pragma unroll
        for (int kc = 0; kc < 4; kc++) afrag[kc] = *(const bf16x8*)(Ap + kc * 32);
#pragma unroll
        for (int n = 0; n < 8; n++) {
            f32x4 acc = (f32x4){0.f, 0.f, 0.f, 0.f};
            const __hip_bfloat16* Bp = Wt1b + (size_t)(n * 16 + rl) * HID + kb * 8;
#pragma unroll
            for (int kc = 0; kc < 4; kc++) {
                bf16x8 bfrag = *(const bf16x8*)(Bp + kc * 32);
                acc = __builtin_amdgcn_mfma_f32_16x16x32_bf16(afrag[kc], bfrag, acc, 0, 0, 0);
            }
            const int col = n * 16 + rl;
            const float bv = b1b[col];
#pragma unroll
            for (int j = 0; j < 4; j++) {
                int row = row0 + wave * 16 + kb * 4 + j;
                if (row < NODES)
                    h1[(size_t)row * HID + col] = __float2bfloat16(fmaxf(acc[j] + bv, 0.f));
            }
        }
    }
}

// ---------------- layer 2 + pool fused: gather -> GEMM -> GEMM -> per-graph atomic sums ----------------

__global__ __launch_bounds__(256) void k_l2p(const uint4* __restrict__ H,
                                             const int* __restrict__ cnt,
                                             const int* __restrict__ csr,
                                             const int* __restrict__ batch,
                                             const __hip_bfloat16* __restrict__ Wt2a,
                                             const float* __restrict__ b2a,
                                             const __hip_bfloat16* __restrict__ Wt2b,
                                             const float* __restrict__ b2b,
                                             float* __restrict__ pooled) {
    __shared__ __hip_bfloat16 ta[16 * LDST];
    __shared__ __hip_bfloat16 tb[16 * LDST];
    __shared__ float t2f[16 * LDSTF];
    __shared__ int sb[16];
    const int row0 = blockIdx.x * 16;
    const int tid = threadIdx.x;

    if (tid < 16) sb[tid] = batch[row0 + tid];

    // phase 1: neighbor-sum gather of h1 rows (unroll 8)
    {
        int n = tid >> 4, q = tid & 15;
        int node = row0 + n;
        int len = cnt[node];
        if (len > CSTRIDE) len = CSTRIDE;
        const int* cp = csr + (size_t)node * CSTRIDE;
        float a[8];
        uint4 v = H[(size_t)node * 16 + q];
        a[0] = __uint_as_float(v.x << 16);
        a[1] = __uint_as_float(v.x & 0xffff0000u);
        a[2] = __uint_as_float(v.y << 16);
        a[3] = __uint_as_float(v.y & 0xffff0000u);
        a[4] = __uint_as_float(v.z << 16);
        a[5] = __uint_as_float(v.z & 0xffff0000u);
        a[6] = __uint_as_float(v.w << 16);
        a[7] = __uint_as_float(v.w & 0xffff0000u);
        int e = 0;
        for (; e + 7 < len; e += 8) {
            uint4 v0 = H[(size_t)cp[e + 0] * 16 + q];
            uint4 v1 = H[(size_t)cp[e + 1] * 16 + q];
            uint4 v2 = H[(size_t)cp[e + 2] * 16 + q];
            uint4 v3 = H[(size_t)cp[e + 3] * 16 + q];
            uint4 v4 = H[(size_t)cp[e + 4] * 16 + q];
            uint4 v5 = H[(size_t)cp[e + 5] * 16 + q];
            uint4 v6 = H[(size_t)cp[e + 6] * 16 + q];
            uint4 v7 = H[(size_t)cp[e + 7] * 16 + q];
            acc8(a, v0); acc8(a, v1); acc8(a, v2); acc8(a, v3);
            acc8(a, v4); acc8(a, v5); acc8(a, v6); acc8(a, v7);
        }
        for (; e + 3 < len; e += 4) {
            uint4 v0 = H[(size_t)cp[e + 0] * 16 + q];
            uint4 v1 = H[(size_t)cp[e + 1] * 16 + q];
            uint4 v2 = H[(size_t)cp[e + 2] * 16 + q];
            uint4 v3 = H[(size_t)cp[e + 3] * 16 + q];
            acc8(a, v0); acc8(a, v1); acc8(a, v2); acc8(a, v3);
        }
        for (; e < len; e++) {
            uint4 vv = H[(size_t)cp[e] * 16 + q];
            acc8(a, vv);
        }
        uint4 o;
        o.x = packbf(a[0], a[1]);
        o.y = packbf(a[2], a[3]);
        o.z = packbf(a[4], a[5]);
        o.w = packbf(a[6], a[7]);
        *(uint4*)&ta[n * LDST + q * 8] = o;
    }
    __syncthreads();

    // phase 2: MFMA x Wt2a -> tb
    mfma_slice16<1, 1>(ta, Wt2a, b2a, tb, nullptr, row0, tid);
    __syncthreads();

    // phase 3: MFMA x Wt2b -> fp32 LDS tile
    {
        const int wave = tid >> 6;
        const int lane = tid & 63;
        const int rl = lane & 15;
        const int kb = lane >> 4;
        bf16x8 afrag[4];
#pragma unroll
        for (int kc = 0; kc < 4; kc++)
            afrag[kc] = *(const bf16x8*)(tb + rl * LDST + kc * 32 + kb * 8);
#pragma unroll
        for (int s = 0; s < 2; s++) {
            const int n = wave * 2 + s;
            f32x4 acc = (f32x4){0.f, 0.f, 0.f, 0.f};
            const __hip_bfloat16* Bp = Wt2b + (size_t)(n * 16 + rl) * HID + kb * 8;
#pragma unroll
            for (int kc = 0; kc < 4; kc++) {
                bf16x8 bfrag = *(const bf16x8*)(Bp + kc * 32);
                acc = __builtin_amdgcn_mfma_f32_16x16x32_bf16(afrag[kc], bfrag, acc, 0, 0, 0);
            }
            const int col = n * 16 + rl;
            const float bv = b2b[col];
#pragma unroll
            for (int j = 0; j < 4; j++)
                t2f[(kb * 4 + j) * LDSTF + col] = fmaxf(acc[j] + bv, 0.f);
        }
    }
    __syncthreads();

    // phase 4: per-graph run-accumulate over rows (batch sorted) -> fp32 atomics
    {
        int c = tid & 127;
        int half = tid >> 7;
        int r0 = half * 8;
        float acc = t2f[r0 * LDSTF + c];
        int gprev = sb[r0];
        for (int r = r0 + 1; r < r0 + 8; r++) {
            int g = sb[r];
            float v = t2f[r * LDSTF + c];
            if (g != gprev) {
                atomicAdd(&pooled[(size_t)gprev * HID + c], acc);
                acc = 0.f;
                gprev = g;
            }
            acc += v;
        }
        atomicAdd(&pooled[(size_t)gprev * HID + c], acc);
    }
}

// ---------------- head: out = (pooled/cnt_g) @ Wtout + bout (fp32 out) ----------------

__device__ __forceinline__ int lower_bound_i(const int* __restrict__ a, int n, int key) {
    int lo = 0, hi = n;
    while (lo < hi) {
        int mid = (lo + hi) >> 1;
        if (a[mid] < key) lo = mid + 1; else hi = mid;
    }
    return lo;
}

__global__ __launch_bounds__(256) void k_head(const float* __restrict__ pooled,
                                              const int* __restrict__ batch,
                                              const __hip_bfloat16* __restrict__ Wt,
                                              const float* __restrict__ bias,
                                              float* __restrict__ out) {
    const int wave = threadIdx.x >> 6;
    const int lane = threadIdx.x & 63;
    const int row0 = blockIdx.x * 64 + wave * 16;
    const int rl = lane & 15;
    const int kb = lane >> 4;

    const int g = row0 + rl;
    int lo = lower_bound_i(batch, NODES, g);
    int hi = lower_bound_i(batch, NODES, g + 1);
    float inv = 1.0f / fmaxf((float)(hi - lo), 1.0f);

    bf16x8 afrag[4];
#pragma unroll
    for (int kc = 0; kc < 4; kc++) {
        const float* Ap = pooled + (size_t)g * HID + kc * 32 + kb * 8;
        unsigned u[4];
#pragma unroll
        for (int p = 0; p < 4; p++) u[p] = packbf(Ap[p * 2] * inv, Ap[p * 2 + 1] * inv);
        afrag[kc] = *(bf16x8*)u;
    }

#pragma unroll
    for (int n = 0; n < 8; n++) {
        f32x4 acc = (f32x4){0.f, 0.f, 0.f, 0.f};
        const __hip_bfloat16* Bp = Wt + (size_t)(n * 16 + rl) * HID + kb * 8;
#pragma unroll
        for (int kc = 0; kc < 4; kc++) {
            bf16x8 bfrag = *(const bf16x8*)(Bp + kc * 32);
            acc = __builtin_amdgcn_mfma_f32_16x16x32_bf16(afrag[kc], bfrag, acc, 0, 0, 0);
        }
        const int col = n * 16 + rl;
        const float bv = bias[col];
#pragma unroll
        for (int j = 0; j < 4; j++)
            out[(size_t)(row0 + kb * 4 + j) * HID + col] = acc[j] + bv;
    }
}

// ---------------- launch ----------------

extern "C" void kernel_launch(void* const* d_in, const int* in_sizes, int n_in,
                              void* d_out, int out_size, void* d_ws, size_t ws_size,
                              hipStream_t stream) {
    const float* x     = (const float*)d_in[0];
    const int*   ei    = (const int*)d_in[1];
    const int*   batch = (const int*)d_in[2];
    const float* W1a = (const float*)d_in[3];
    const float* b1a = (const float*)d_in[4];
    const float* W1b = (const float*)d_in[5];
    const float* b1b = (const float*)d_in[6];
    const float* W2a = (const float*)d_in[7];
    const float* b2a = (const float*)d_in[8];
    const float* W2b = (const float*)d_in[9];
    const float* b2b = (const float*)d_in[10];
    const float* Wout = (const float*)d_in[11];
    const float* bout = (const float*)d_in[12];

    const int* src = ei;
    const int* dst = ei + EDGES;

    char* w = (char*)d_ws;
    auto alloc = [&](size_t bytes) {
        void* p = (void*)w;
        w += (bytes + 255) & ~(size_t)255;
        return p;
    };
    __hip_bfloat16* h1 = (__hip_bfloat16*)alloc((size_t)NODES * HID * 2);  // 25.6 MB
    float* xf = (float*)alloc((size_t)NODES * 16 * 4);                     // 6.4 MB
    int* cnt = (int*)alloc((size_t)NODES * 4);
    float* pooled = (float*)alloc((size_t)GRAPHS * HID * 4);               // 2 MB
    __hip_bfloat16* Wt1b = (__hip_bfloat16*)alloc(HID * HID * 2);
    __hip_bfloat16* Wt2a = (__hip_bfloat16*)alloc(HID * HID * 2);
    __hip_bfloat16* Wt2b = (__hip_bfloat16*)alloc(HID * HID * 2);
    __hip_bfloat16* Wtout = (__hip_bfloat16*)alloc(HID * HID * 2);
    int* csr = (int*)alloc((size_t)NODES * CSTRIDE * 4);                   // 25.6 MB
    float* out = (float*)d_out;

    // ---- prep ----
    k_w_cvt4<<<256, 256, 0, stream>>>(W1b, W2a, W2b, Wout, Wt1b, Wt2a, Wt2b, Wtout);
    k_prep2<<<(NODES * 16 + 255) / 256, 256, 0, stream>>>(cnt, pooled, x, xf);

    // ---- bucket-CSR build (single-pass, partitioned) ----
    k_fill_fx<<<NPART * BPG, 256, 0, stream>>>((const i32x4*)src, (const i32x4*)dst, cnt, csr);

    // ---- layer 1 (64 nodes/block, float4 gather) ----
    k_l1<<<(NODES + 63) / 64, 256, 0, stream>>>((const float4*)xf, cnt, csr,
                                                W1a, b1a, Wt1b, b1b, h1);

    // ---- layer 2 + pool ----
    k_l2p<<<NODES / 16, 256, 0, stream>>>((const uint4*)h1, cnt, csr, batch,
                                          Wt2a, b2a, Wt2b, b2b, pooled);

    // ---- head ----
    k_head<<<GRAPHS / 64, 256, 0, stream>>>(pooled, batch, Wtout, bout, out);
}

// Round 17
// 254.416 us; speedup vs baseline: 1.0490x; 1.0490x over previous
//
#include <hip/hip_runtime.h>
#include <hip/hip_bf16.h>

#define NODES  100000
#define EDGES  1600000
#define GRAPHS 4096
#define HID    128
#define INDIM  14
#define NPART  8
#define PART_SZ ((NODES + NPART - 1) / NPART)  // 12500
#define BPG    256        // blocks per partition group (fill)
#define CSTRIDE 64        // fixed CSR bucket stride; P(deg>=64 | Poisson(16)) ~ 2e-18
#define LDST   136        // LDS tile row stride in bf16 (272B: 16B-aligned)
#define LDSTF  132        // fp32 LDS tile row stride

typedef float f32x4 __attribute__((ext_vector_type(4)));
typedef short bf16x8 __attribute__((ext_vector_type(8)));
typedef int   i32x4 __attribute__((ext_vector_type(4)));

__device__ __forceinline__ unsigned packbf(float a, float b) {
    __hip_bfloat162 t;
    t.x = __float2bfloat16(a);
    t.y = __float2bfloat16(b);
    return *(unsigned*)&t;
}
__device__ __forceinline__ void acc8(float* a, uint4 v) {
    a[0] += __uint_as_float(v.x << 16);
    a[1] += __uint_as_float(v.x & 0xffff0000u);
    a[2] += __uint_as_float(v.y << 16);
    a[3] += __uint_as_float(v.y & 0xffff0000u);
    a[4] += __uint_as_float(v.z << 16);
    a[5] += __uint_as_float(v.z & 0xffff0000u);
    a[6] += __uint_as_float(v.w << 16);
    a[7] += __uint_as_float(v.w & 0xffff0000u);
}

// ---------------- prep: weight cvt + zero cnt/pooled (one launch) ----------------
// blocks [0,256): 4 weights W[k][n] fp32 -> Wt[n][k] bf16
// blocks [256, 256+2048): zero cnt (100000) + pooled (524288)

__global__ void k_prep(const float* __restrict__ W1b, const float* __restrict__ W2a,
                       const float* __restrict__ W2b, const float* __restrict__ Wout,
                       __hip_bfloat16* __restrict__ T1b, __hip_bfloat16* __restrict__ T2a,
                       __hip_bfloat16* __restrict__ T2b, __hip_bfloat16* __restrict__ Tout,
                       int* __restrict__ cnt, float* __restrict__ pooled) {
    int b = blockIdx.x;
    if (b < 256) {
        int which = b >> 6;
        int idx = (b & 63) * 256 + threadIdx.x;  // 16384 per matrix
        const float* W = which == 0 ? W1b : which == 1 ? W2a : which == 2 ? W2b : Wout;
        __hip_bfloat16* T = which == 0 ? T1b : which == 1 ? T2a : which == 2 ? T2b : Tout;
        int n = idx & 127, k = idx >> 7;
        T[n * HID + k] = __float2bfloat16(W[k * HID + n]);
    } else {
        int i = (b - 256) * 256 + threadIdx.x;
        if (i < NODES) cnt[i] = 0;
        if (i < GRAPHS * HID) pooled[i] = 0.f;
    }
}

// ---------------- bucket-CSR build (single-pass, XCD-range-partitioned) ----------------
// src4 loaded ONLY if some lane-local edge is in this group's dst range (~41% of packets).

__global__ __launch_bounds__(256) void k_fill_fx(const i32x4* __restrict__ src4,
                                                 const i32x4* __restrict__ dst4,
                                                 int* __restrict__ cnt,
                                                 int* __restrict__ csr) {
    const int g = blockIdx.x & (NPART - 1);
    const int blk = blockIdx.x >> 3;
    const int lo = g * PART_SZ;
    const int n4 = EDGES / 4;
    for (int e4 = blk * 256 + threadIdx.x; e4 < n4; e4 += BPG * 256) {
        i32x4 d = __builtin_nontemporal_load(&dst4[e4]);
        bool in0 = (unsigned)(d[0] - lo) < PART_SZ;
        bool in1 = (unsigned)(d[1] - lo) < PART_SZ;
        bool in2 = (unsigned)(d[2] - lo) < PART_SZ;
        bool in3 = (unsigned)(d[3] - lo) < PART_SZ;
        if (in0 | in1 | in2 | in3) {
            i32x4 s = __builtin_nontemporal_load(&src4[e4]);
#pragma unroll
            for (int j = 0; j < 4; j++) {
                int dj = d[j];
                if ((unsigned)(dj - lo) < PART_SZ) {
                    int pos = atomicAdd(&cnt[dj], 1);
                    if (pos < CSTRIDE) csr[dj * CSTRIDE + pos] = s[j];
                }
            }
        }
    }
}

// ---------------- MFMA slice helper (16-row tile, wave does 32-col slice) ----------------
// A frag: lane rl=l&15 -> row rl, kb=l>>4 -> k = kc*32+kb*8..+7.
// C/D: col = n*16+rl, row = kb*4+j  [verified mapping].

template <int RELU, int TO_LDS>
__device__ __forceinline__ void mfma_slice16(const __hip_bfloat16* lds_in,
                                             const __hip_bfloat16* __restrict__ Wt,
                                             const float* __restrict__ bias,
                                             __hip_bfloat16* lds_out,
                                             __hip_bfloat16* __restrict__ gout,
                                             int row0, int tid) {
    const int wave = tid >> 6;
    const int lane = tid & 63;
    const int rl = lane & 15;
    const int kb = lane >> 4;

    bf16x8 afrag[4];
#pragma unroll
    for (int kc = 0; kc < 4; kc++)
        afrag[kc] = *(const bf16x8*)(lds_in + rl * LDST + kc * 32 + kb * 8);

#pragma unroll
    for (int s = 0; s < 2; s++) {
        const int n = wave * 2 + s;
        f32x4 acc = (f32x4){0.f, 0.f, 0.f, 0.f};
        const __hip_bfloat16* Bp = Wt + (size_t)(n * 16 + rl) * HID + kb * 8;
#pragma unroll
        for (int kc = 0; kc < 4; kc++) {
            bf16x8 bfrag = *(const bf16x8*)(Bp + kc * 32);
            acc = __builtin_amdgcn_mfma_f32_16x16x32_bf16(afrag[kc], bfrag, acc, 0, 0, 0);
        }
        const int col = n * 16 + rl;
        const float bv = bias[col];
#pragma unroll
        for (int j = 0; j < 4; j++) {
            int rloc = kb * 4 + j;
            float v = acc[j] + bv;
            if (RELU) v = fmaxf(v, 0.f);
            if (TO_LDS)
                lds_out[rloc * LDST + col] = __float2bfloat16(v);
            else
                gout[(size_t)(row0 + rloc) * HID + col] = __float2bfloat16(v);
        }
    }
}

// ---------------- layer 1 fused: 16 nodes/block (fp32 x gather, R15-proven) ----------------

__global__ __launch_bounds__(256) void k_l1(const float* __restrict__ x,
                                            const int* __restrict__ cnt,
                                            const int* __restrict__ csr,
                                            const float* __restrict__ W1a,
                                            const float* __restrict__ b1a,
                                            const __hip_bfloat16* __restrict__ Wt1b,
                                            const float* __restrict__ b1b,
                                            __hip_bfloat16* __restrict__ h1) {
    __shared__ float p14[16][16];
    __shared__ __hip_bfloat16 t[16 * LDST];
    const int row0 = blockIdx.x * 16;
    const int tid = threadIdx.x;

    {
        int n = tid >> 4, d = tid & 15;
        int node = row0 + n;
        if (d < INDIM) {
            int len = cnt[node];
            if (len > CSTRIDE) len = CSTRIDE;
            const int* cp = csr + (size_t)node * CSTRIDE;
            float acc = x[node * INDIM + d];
            int e = 0;
            for (; e + 7 < len; e += 8) {
                int s0 = cp[e], s1 = cp[e + 1], s2 = cp[e + 2], s3 = cp[e + 3];
                int s4 = cp[e + 4], s5 = cp[e + 5], s6 = cp[e + 6], s7 = cp[e + 7];
                float v0 = x[s0 * INDIM + d], v1 = x[s1 * INDIM + d];
                float v2 = x[s2 * INDIM + d], v3 = x[s3 * INDIM + d];
                float v4 = x[s4 * INDIM + d], v5 = x[s5 * INDIM + d];
                float v6 = x[s6 * INDIM + d], v7 = x[s7 * INDIM + d];
                acc += ((v0 + v1) + (v2 + v3)) + ((v4 + v5) + (v6 + v7));
            }
            for (; e + 3 < len; e += 4) {
                int s0 = cp[e], s1 = cp[e + 1], s2 = cp[e + 2], s3 = cp[e + 3];
                acc += x[s0 * INDIM + d] + x[s1 * INDIM + d] +
                       x[s2 * INDIM + d] + x[s3 * INDIM + d];
            }
            for (; e < len; e++) acc += x[cp[e] * INDIM + d];
            p14[n][d] = acc;
        }
    }
    __syncthreads();

    for (int i = tid; i < 512; i += 256) {
        int r = i >> 5, c4 = (i & 31) << 2;
        float4 bv = *(const float4*)&b1a[c4];
        float ax = bv.x, ay = bv.y, az = bv.z, aw = bv.w;
#pragma unroll
        for (int k = 0; k < INDIM; k++) {
            float a = p14[r][k];
            float4 w = *(const float4*)&W1a[k * HID + c4];
            ax += a * w.x; ay += a * w.y; az += a * w.z; aw += a * w.w;
        }
        unsigned p0 = packbf(fmaxf(ax, 0.f), fmaxf(ay, 0.f));
        unsigned p1 = packbf(fmaxf(az, 0.f), fmaxf(aw, 0.f));
        *(uint2*)&t[r * LDST + c4] = make_uint2(p0, p1);
    }
    __syncthreads();

    mfma_slice16<1, 0>(t, Wt1b, b1b, nullptr, h1, row0, tid);
}

// ---------------- layer 2 + pool fused: gather -> GEMM -> GEMM -> per-graph atomic sums ----------------

__global__ __launch_bounds__(256) void k_l2p(const uint4* __restrict__ H,
                                             const int* __restrict__ cnt,
                                             const int* __restrict__ csr,
                                             const int* __restrict__ batch,
                                             const __hip_bfloat16* __restrict__ Wt2a,
                                             const float* __restrict__ b2a,
                                             const __hip_bfloat16* __restrict__ Wt2b,
                                             const float* __restrict__ b2b,
                                             float* __restrict__ pooled) {
    __shared__ __hip_bfloat16 ta[16 * LDST];
    __shared__ __hip_bfloat16 tb[16 * LDST];
    __shared__ float t2f[16 * LDSTF];
    __shared__ int sb[16];
    const int row0 = blockIdx.x * 16;
    const int tid = threadIdx.x;

    if (tid < 16) sb[tid] = batch[row0 + tid];

    // phase 1: neighbor-sum gather of h1 rows (unroll 8)
    {
        int n = tid >> 4, q = tid & 15;
        int node = row0 + n;
        int len = cnt[node];
        if (len > CSTRIDE) len = CSTRIDE;
        const int* cp = csr + (size_t)node * CSTRIDE;
        float a[8];
        uint4 v = H[(size_t)node * 16 + q];
        a[0] = __uint_as_float(v.x << 16);
        a[1] = __uint_as_float(v.x & 0xffff0000u);
        a[2] = __uint_as_float(v.y << 16);
        a[3] = __uint_as_float(v.y & 0xffff0000u);
        a[4] = __uint_as_float(v.z << 16);
        a[5] = __uint_as_float(v.z & 0xffff0000u);
        a[6] = __uint_as_float(v.w << 16);
        a[7] = __uint_as_float(v.w & 0xffff0000u);
        int e = 0;
        for (; e + 7 < len; e += 8) {
            uint4 v0 = H[(size_t)cp[e + 0] * 16 + q];
            uint4 v1 = H[(size_t)cp[e + 1] * 16 + q];
            uint4 v2 = H[(size_t)cp[e + 2] * 16 + q];
            uint4 v3 = H[(size_t)cp[e + 3] * 16 + q];
            uint4 v4 = H[(size_t)cp[e + 4] * 16 + q];
            uint4 v5 = H[(size_t)cp[e + 5] * 16 + q];
            uint4 v6 = H[(size_t)cp[e + 6] * 16 + q];
            uint4 v7 = H[(size_t)cp[e + 7] * 16 + q];
            acc8(a, v0); acc8(a, v1); acc8(a, v2); acc8(a, v3);
            acc8(a, v4); acc8(a, v5); acc8(a, v6); acc8(a, v7);
        }
        for (; e + 3 < len; e += 4) {
            uint4 v0 = H[(size_t)cp[e + 0] * 16 + q];
            uint4 v1 = H[(size_t)cp[e + 1] * 16 + q];
            uint4 v2 = H[(size_t)cp[e + 2] * 16 + q];
            uint4 v3 = H[(size_t)cp[e + 3] * 16 + q];
            acc8(a, v0); acc8(a, v1); acc8(a, v2); acc8(a, v3);
        }
        for (; e < len; e++) {
            uint4 vv = H[(size_t)cp[e] * 16 + q];
            acc8(a, vv);
        }
        uint4 o;
        o.x = packbf(a[0], a[1]);
        o.y = packbf(a[2], a[3]);
        o.z = packbf(a[4], a[5]);
        o.w = packbf(a[6], a[7]);
        *(uint4*)&ta[n * LDST + q * 8] = o;
    }
    __syncthreads();

    // phase 2: MFMA x Wt2a -> tb
    mfma_slice16<1, 1>(ta, Wt2a, b2a, tb, nullptr, row0, tid);
    __syncthreads();

    // phase 3: MFMA x Wt2b -> fp32 LDS tile
    {
        const int wave = tid >> 6;
        const int lane = tid & 63;
        const int rl = lane & 15;
        const int kb = lane >> 4;
        bf16x8 afrag[4];
#pragma unroll
        for (int kc = 0; kc < 4; kc++)
            afrag[kc] = *(const bf16x8*)(tb + rl * LDST + kc * 32 + kb * 8);
#pragma unroll
        for (int s = 0; s < 2; s++) {
            const int n = wave * 2 + s;
            f32x4 acc = (f32x4){0.f, 0.f, 0.f, 0.f};
            const __hip_bfloat16* Bp = Wt2b + (size_t)(n * 16 + rl) * HID + kb * 8;
#pragma unroll
            for (int kc = 0; kc < 4; kc++) {
                bf16x8 bfrag = *(const bf16x8*)(Bp + kc * 32);
                acc = __builtin_amdgcn_mfma_f32_16x16x32_bf16(afrag[kc], bfrag, acc, 0, 0, 0);
            }
            const int col = n * 16 + rl;
            const float bv = b2b[col];
#pragma unroll
            for (int j = 0; j < 4; j++)
                t2f[(kb * 4 + j) * LDSTF + col] = fmaxf(acc[j] + bv, 0.f);
        }
    }
    __syncthreads();

    // phase 4: per-graph run-accumulate over rows (batch sorted) -> fp32 atomics
    {
        int c = tid & 127;
        int half = tid >> 7;
        int r0 = half * 8;
        float acc = t2f[r0 * LDSTF + c];
        int gprev = sb[r0];
        for (int r = r0 + 1; r < r0 + 8; r++) {
            int g = sb[r];
            float v = t2f[r * LDSTF + c];
            if (g != gprev) {
                atomicAdd(&pooled[(size_t)gprev * HID + c], acc);
                acc = 0.f;
                gprev = g;
            }
            acc += v;
        }
        atomicAdd(&pooled[(size_t)gprev * HID + c], acc);
    }
}

// ---------------- head: out = (pooled/cnt_g) @ Wtout + bout (fp32 out) ----------------

__device__ __forceinline__ int lower_bound_i(const int* __restrict__ a, int n, int key) {
    int lo = 0, hi = n;
    while (lo < hi) {
        int mid = (lo + hi) >> 1;
        if (a[mid] < key) lo = mid + 1; else hi = mid;
    }
    return lo;
}

__global__ __launch_bounds__(256) void k_head(const float* __restrict__ pooled,
                                              const int* __restrict__ batch,
                                              const __hip_bfloat16* __restrict__ Wt,
                                              const float* __restrict__ bias,
                                              float* __restrict__ out) {
    const int wave = threadIdx.x >> 6;
    const int lane = threadIdx.x & 63;
    const int row0 = blockIdx.x * 64 + wave * 16;
    const int rl = lane & 15;
    const int kb = lane >> 4;

    const int g = row0 + rl;
    int lo = lower_bound_i(batch, NODES, g);
    int hi = lower_bound_i(batch, NODES, g + 1);
    float inv = 1.0f / fmaxf((float)(hi - lo), 1.0f);

    bf16x8 afrag[4];
#pragma unroll
    for (int kc = 0; kc < 4; kc++) {
        const float* Ap = pooled + (size_t)g * HID + kc * 32 + kb * 8;
        unsigned u[4];
#pragma unroll
        for (int p = 0; p < 4; p++) u[p] = packbf(Ap[p * 2] * inv, Ap[p * 2 + 1] * inv);
        afrag[kc] = *(bf16x8*)u;
    }

#pragma unroll
    for (int n = 0; n < 8; n++) {
        f32x4 acc = (f32x4){0.f, 0.f, 0.f, 0.f};
        const __hip_bfloat16* Bp = Wt + (size_t)(n * 16 + rl) * HID + kb * 8;
#pragma unroll
        for (int kc = 0; kc < 4; kc++) {
            bf16x8 bfrag = *(const bf16x8*)(Bp + kc * 32);
            acc = __builtin_amdgcn_mfma_f32_16x16x32_bf16(afrag[kc], bfrag, acc, 0, 0, 0);
        }
        const int col = n * 16 + rl;
        const float bv = bias[col];
#pragma unroll
        for (int j = 0; j < 4; j++)
            out[(size_t)(row0 + kb * 4 + j) * HID + col] = acc[j] + bv;
    }
}

// ---------------- launch ----------------

extern "C" void kernel_launch(void* const* d_in, const int* in_sizes, int n_in,
                              void* d_out, int out_size, void* d_ws, size_t ws_size,
                              hipStream_t stream) {
    const float* x     = (const float*)d_in[0];
    const int*   ei    = (const int*)d_in[1];
    const int*   batch = (const int*)d_in[2];
    const float* W1a = (const float*)d_in[3];
    const float* b1a = (const float*)d_in[4];
    const float* W1b = (const float*)d_in[5];
    const float* b1b = (const float*)d_in[6];
    const float* W2a = (const float*)d_in[7];
    const float* b2a = (const float*)d_in[8];
    const float* W2b = (const float*)d_in[9];
    const float* b2b = (const float*)d_in[10];
    const float* Wout = (const float*)d_in[11];
    const float* bout = (const float*)d_in[12];

    const int* src = ei;
    const int* dst = ei + EDGES;

    char* w = (char*)d_ws;
    auto alloc = [&](size_t bytes) {
        void* p = (void*)w;
        w += (bytes + 255) & ~(size_t)255;
        return p;
    };
    __hip_bfloat16* h1 = (__hip_bfloat16*)alloc((size_t)NODES * HID * 2);  // 25.6 MB
    int* cnt = (int*)alloc((size_t)NODES * 4);
    float* pooled = (float*)alloc((size_t)GRAPHS * HID * 4);               // 2 MB
    __hip_bfloat16* Wt1b = (__hip_bfloat16*)alloc(HID * HID * 2);
    __hip_bfloat16* Wt2a = (__hip_bfloat16*)alloc(HID * HID * 2);
    __hip_bfloat16* Wt2b = (__hip_bfloat16*)alloc(HID * HID * 2);
    __hip_bfloat16* Wtout = (__hip_bfloat16*)alloc(HID * HID * 2);
    int* csr = (int*)alloc((size_t)NODES * CSTRIDE * 4);                   // 25.6 MB
    float* out = (float*)d_out;

    // ---- prep: weights + zero cnt/pooled (one launch) ----
    k_prep<<<256 + 2048, 256, 0, stream>>>(W1b, W2a, W2b, Wout, Wt1b, Wt2a, Wt2b, Wtout,
                                           cnt, pooled);

    // ---- bucket-CSR build (single-pass, partitioned, conditional src read) ----
    k_fill_fx<<<NPART * BPG, 256, 0, stream>>>((const i32x4*)src, (const i32x4*)dst, cnt, csr);

    // ---- layer 1 ----
    k_l1<<<NODES / 16, 256, 0, stream>>>(x, cnt, csr, W1a, b1a, Wt1b, b1b, h1);

    // ---- layer 2 + pool ----
    k_l2p<<<NODES / 16, 256, 0, stream>>>((const uint4*)h1, cnt, csr, batch,
                                          Wt2a, b2a, Wt2b, b2b, pooled);

    // ---- head ----
    k_head<<<GRAPHS / 64, 256, 0, stream>>>(pooled, batch, Wtout, bout, out);
}